// Round 3
// baseline (282.541 us; speedup 1.0000x reference)
//
#include <hip/hip_runtime.h>

#define T_SEQ 2048
#define NH    6
#define HD    128
#define CDIM  768
#define NQKV  2304
#define MROWS 8192   // B*T = 4*2048

typedef __attribute__((ext_vector_type(8))) short bf16x8;
typedef __attribute__((ext_vector_type(4))) float f32x4;

__device__ __forceinline__ unsigned short f2bf(float f){
  unsigned int u = __builtin_bit_cast(unsigned int, f);
  u += 0x7fffu + ((u >> 16) & 1u);          // round-to-nearest-even
  return (unsigned short)(u >> 16);
}
__device__ __forceinline__ float bf2f(unsigned short h){
  unsigned int u = ((unsigned int)h) << 16;
  return __builtin_bit_cast(float, u);
}

// async global->LDS, 16B per lane; lds dest must be wave-uniform base (+lane*16)
__device__ __forceinline__ void gload_lds16(const void* g, void* l){
  __builtin_amdgcn_global_load_lds(
      (const __attribute__((address_space(1))) unsigned int*)g,
      (__attribute__((address_space(3))) unsigned int*)l, 16, 0, 0);
}

// ---------------- f32 -> bf16 conversion (vectorized) ----------------
__global__ __launch_bounds__(256) void cvt_f32_bf16(
    const float* __restrict__ in, unsigned short* __restrict__ out, int n4){
  int i = blockIdx.x * 256 + threadIdx.x;
  if (i >= n4) return;
  float4 v = reinterpret_cast<const float4*>(in)[i];
  ushort4 o;
  o.x = f2bf(v.x); o.y = f2bf(v.y); o.z = f2bf(v.z); o.w = f2bf(v.w);
  reinterpret_cast<ushort4*>(out)[i] = o;
}

// ---------------- GEMM: C = A(MxK,bf16) * B(NxK,bf16)^T ----------------
// m97 structure: 128x128 tile, BK=64, global_load_lds(16B) into LINEAR LDS.
template<int BF16OUT>
__global__ __launch_bounds__(256) void gemm_bt(
    const unsigned short* __restrict__ A,
    const unsigned short* __restrict__ B,
    void* __restrict__ Cv, int M, int N, int K)
{
  __shared__ unsigned short As[128 * 64];   // linear [row][64], row stride 128B
  __shared__ unsigned short Bs[128 * 64];
  const int tid  = threadIdx.x;
  const int lane = tid & 63;
  const int wave = tid >> 6;
  const int wm = wave >> 1, wn = wave & 1;
  const int lr = lane & 15, lg = lane >> 4;
  const int lrow = lane >> 3;           // 0..7  (staging row within 8-row seg)
  const int lcol = (lane & 7) * 8;      // 0..56 (staging col, 8 bf16)
  const int row0 = blockIdx.x * 128, col0 = blockIdx.y * 128;

  f32x4 acc[4][4];
  const f32x4 z = {0.f, 0.f, 0.f, 0.f};
  #pragma unroll
  for (int i = 0; i < 4; ++i)
    #pragma unroll
    for (int j = 0; j < 4; ++j) acc[i][j] = z;

  for (int k0 = 0; k0 < K; k0 += 64){
    // stage: each wave-instr fills a 1KB LDS segment (8 rows x 64 cols)
    #pragma unroll
    for (int i = 0; i < 4; ++i){
      int seg = wave * 4 + i;                 // 0..15 -> rows seg*8..seg*8+7
      int r = seg * 8 + lrow;
      gload_lds16(&A[(size_t)(row0 + r) * K + k0 + lcol], &As[seg * 512]);
      gload_lds16(&B[(size_t)(col0 + r) * K + k0 + lcol], &Bs[seg * 512]);
    }
    __syncthreads();
    #pragma unroll
    for (int kk = 0; kk < 64; kk += 32){
      bf16x8 af[4], bfr[4];
      #pragma unroll
      for (int mi = 0; mi < 4; ++mi)
        af[mi] = *reinterpret_cast<const bf16x8*>(&As[(wm*64 + mi*16 + lr) * 64 + kk + lg*8]);
      #pragma unroll
      for (int ni = 0; ni < 4; ++ni)
        bfr[ni] = *reinterpret_cast<const bf16x8*>(&Bs[(wn*64 + ni*16 + lr) * 64 + kk + lg*8]);
      #pragma unroll
      for (int mi = 0; mi < 4; ++mi)
        #pragma unroll
        for (int ni = 0; ni < 4; ++ni)
          acc[mi][ni] = __builtin_amdgcn_mfma_f32_16x16x32_bf16(af[mi], bfr[ni], acc[mi][ni], 0, 0, 0);
    }
    __syncthreads();
  }
  #pragma unroll
  for (int mi = 0; mi < 4; ++mi){
    #pragma unroll
    for (int ni = 0; ni < 4; ++ni){
      #pragma unroll
      for (int r = 0; r < 4; ++r){
        int row = row0 + wm*64 + mi*16 + lg*4 + r;   // C/D: row=(l>>4)*4+reg
        int col = col0 + wn*64 + ni*16 + lr;         //       col=l&15
        if (BF16OUT)
          reinterpret_cast<unsigned short*>(Cv)[(size_t)row * N + col] = f2bf(acc[mi][ni][r]);
        else
          reinterpret_cast<float*>(Cv)[(size_t)row * N + col] = acc[mi][ni][r];
      }
    }
  }
}

// ---------------- RoPE + RMSNorm for Q,K; writes (B,H,T,D) bf16 ----------------
__global__ __launch_bounds__(256) void rope_rms(
    const unsigned short* __restrict__ QKVb,
    const float* __restrict__ cosp, const float* __restrict__ sinp,
    unsigned short* __restrict__ Qb, unsigned short* __restrict__ Kb)
{
  const int bt    = blockIdx.x;            // b*T + t
  const int task  = blockIdx.y * 4 + (threadIdx.x >> 6);   // 0..11
  const int which = task / NH;             // 0=q, 1=k
  const int h     = task % NH;
  const int t     = bt & (T_SEQ - 1);
  const int b     = bt >> 11;
  const int lane  = threadIdx.x & 63;      // 0..63
  const unsigned short* src = QKVb + (size_t)bt * NQKV + which * CDIM + h * HD;
  float x1 = bf2f(src[lane]);
  float x2 = bf2f(src[lane + 64]);
  float c = cosp[t * 64 + lane];
  float s = sinp[t * 64 + lane];
  float y1 = x1 * c + x2 * s;
  float y2 = x2 * c - x1 * s;
  float ss = y1 * y1 + y2 * y2;
  #pragma unroll
  for (int off = 1; off < 64; off <<= 1) ss += __shfl_xor(ss, off);
  float inv = rsqrtf(ss * (1.0f / 128.0f) + 1e-15f);
  unsigned short* dst = (which ? Kb : Qb) + ((size_t)(b * NH + h) * T_SEQ + t) * HD;
  dst[lane]      = f2bf(y1 * inv);
  dst[lane + 64] = f2bf(y2 * inv);
}

// ---------------- V transpose: QKV v-slice (B,T,H,D) -> Vt (B*H, D, T) ----------------
__global__ __launch_bounds__(256) void transpose_v(
    const unsigned short* __restrict__ QKVb, unsigned short* __restrict__ Vt)
{
  __shared__ unsigned short tile[64][66];
  const int tid = threadIdx.x;
  const int t0  = blockIdx.x * 64;          // 32 tiles along T
  const int hd  = blockIdx.y;               // 0..11 : (head, d-half)
  const int b   = blockIdx.z;               // 0..3
  const int h = hd >> 1, dhalf = (hd & 1) * 64;
  const unsigned short* src = QKVb + (size_t)b * T_SEQ * NQKV + 2 * CDIM + h * HD + dhalf;
  #pragma unroll
  for (int it = 0; it < 2; ++it){
    int ch = tid + it * 256;                // 64 rows x 8 chunks
    int r = ch >> 3, cc = (ch & 7) * 8;
    *reinterpret_cast<int4*>(&tile[r][cc]) =
        *reinterpret_cast<const int4*>(&src[(size_t)(t0 + r) * NQKV + cc]);
  }
  __syncthreads();
  unsigned short* dst = Vt + ((size_t)(b * NH + h) * HD + dhalf) * T_SEQ + t0;
  #pragma unroll
  for (int it = 0; it < 2; ++it){
    int ch = tid + it * 256;                // 64 d-rows x 8 chunks
    int d = ch >> 3, cc = (ch & 7) * 8;
    union { int4 v; unsigned short u[8]; } w;
    #pragma unroll
    for (int j = 0; j < 8; ++j) w.u[j] = tile[cc + j][d];
    *reinterpret_cast<int4*>(&dst[(size_t)d * T_SEQ + cc]) = w.v;
  }
}

// ---------------- causal flash attention ----------------
// block: 4 waves, QBLK=64 (16 q-rows/wave), KVBLK=64, D=128. V pre-transposed.
// Ps (P relayout) aliases the Ks region: Ks is dead after QK^T, Ps is dead
// by the end-of-iteration barrier. LDS = 35840B -> 4 blocks/CU.
__global__ __launch_bounds__(256, 4) void attn_fwd(
    const unsigned short* __restrict__ Qb,
    const unsigned short* __restrict__ Kb,
    const unsigned short* __restrict__ Vt,     // (B*H, D, T)
    unsigned short* __restrict__ AO)
{
  __shared__ unsigned short Ks[64][136];    // K tile [kv][d], +8 pad (17408B)
  __shared__ unsigned short Vs[128][72];    // V^T tile [d][kv], +8 pad (18432B)
  const int tid = threadIdx.x;
  const int lane = tid & 63, wave = tid >> 6;
  const int lr = lane & 15, lg = lane >> 4;
  // per-wave P buffer aliased onto Ks: 16 rows x 68 f32 = 4352B each
  float* Ps = reinterpret_cast<float*>(&Ks[0][0]) + wave * 1088;
  const int bh = blockIdx.y;
  const int b = bh / NH, h = bh % NH;
  const int q0 = (gridDim.x - 1 - blockIdx.x) * 64;   // big causal blocks first
  const int qw = q0 + wave * 16;
  const unsigned short* Qp = Qb + (size_t)bh * T_SEQ * HD;
  const unsigned short* Kp = Kb + (size_t)bh * T_SEQ * HD;
  const unsigned short* Vp = Vt + (size_t)bh * HD * T_SEQ;

  // Q fragments in registers: A[m=l&15][k=8*(l>>4)+j], 4 k-chunks of 32
  bf16x8 qf[4];
  #pragma unroll
  for (int c4 = 0; c4 < 4; ++c4)
    qf[c4] = *reinterpret_cast<const bf16x8*>(&Qp[(size_t)(qw + lr) * HD + c4 * 32 + lg * 8]);

  const f32x4 z = {0.f, 0.f, 0.f, 0.f};
  f32x4 o[8];
  #pragma unroll
  for (int dt = 0; dt < 8; ++dt) o[dt] = z;
  float mrun[4], lrun[4];
  #pragma unroll
  for (int r = 0; r < 4; ++r){ mrun[r] = -__builtin_inff(); lrun[r] = 0.f; }
  const float scl = 0.08838834764831845f;   // 1/sqrt(128)

  for (int kv0 = 0; kv0 < q0 + 64; kv0 += 64){
    // ---- stage K rows and V^T rows (both coalesced) ----
    #pragma unroll
    for (int it = 0; it < 4; ++it){
      int ch = tid + it * 256;               // K: 64 rows x 16 chunks
      int r = ch >> 4, cc = (ch & 15) * 8;
      *reinterpret_cast<int4*>(&Ks[r][cc]) =
          *reinterpret_cast<const int4*>(&Kp[(size_t)(kv0 + r) * HD + cc]);
      int rv = ch >> 3, cv = (ch & 7) * 8;   // V: 128 d-rows x 8 chunks
      *reinterpret_cast<int4*>(&Vs[rv][cv]) =
          *reinterpret_cast<const int4*>(&Vp[(size_t)rv * T_SEQ + kv0 + cv]);
    }
    __syncthreads();

    // ---- S = Q K^T (16 x 64) ----
    f32x4 s[4];
    #pragma unroll
    for (int nt = 0; nt < 4; ++nt) s[nt] = z;
    #pragma unroll
    for (int c4 = 0; c4 < 4; ++c4){
      #pragma unroll
      for (int nt = 0; nt < 4; ++nt){
        bf16x8 kf = *reinterpret_cast<const bf16x8*>(&Ks[nt * 16 + lr][c4 * 32 + lg * 8]);
        s[nt] = __builtin_amdgcn_mfma_f32_16x16x32_bf16(qf[c4], kf, s[nt], 0, 0, 0);
      }
    }
    __syncthreads();   // all waves done reading Ks; Ps may now overwrite it

    // ---- scale + causal mask ----
    if (kv0 + 63 > qw){
      #pragma unroll
      for (int nt = 0; nt < 4; ++nt){
        int kg = kv0 + nt * 16 + lr;
        #pragma unroll
        for (int r = 0; r < 4; ++r){
          int qg = qw + lg * 4 + r;
          s[nt][r] = (kg <= qg) ? s[nt][r] * scl : -__builtin_inff();
        }
      }
    } else {
      #pragma unroll
      for (int nt = 0; nt < 4; ++nt)
        #pragma unroll
        for (int r = 0; r < 4; ++r) s[nt][r] *= scl;
    }

    // ---- online softmax (per row; 16-lane shuffle reductions) ----
    float pm[4], sc[4], rs[4];
    #pragma unroll
    for (int r = 0; r < 4; ++r)
      pm[r] = fmaxf(fmaxf(s[0][r], s[1][r]), fmaxf(s[2][r], s[3][r]));
    #pragma unroll
    for (int off = 1; off < 16; off <<= 1){
      #pragma unroll
      for (int r = 0; r < 4; ++r) pm[r] = fmaxf(pm[r], __shfl_xor(pm[r], off));
    }
    #pragma unroll
    for (int r = 0; r < 4; ++r){
      float mn = fmaxf(mrun[r], pm[r]);
      sc[r] = (mrun[r] == -__builtin_inff()) ? 0.f : __expf(mrun[r] - mn);
      mrun[r] = mn;
      rs[r] = 0.f;
    }
    #pragma unroll
    for (int nt = 0; nt < 4; ++nt)
      #pragma unroll
      for (int r = 0; r < 4; ++r){
        float p = __expf(s[nt][r] - mrun[r]);
        s[nt][r] = p;
        rs[r] += p;
      }
    #pragma unroll
    for (int off = 1; off < 16; off <<= 1){
      #pragma unroll
      for (int r = 0; r < 4; ++r) rs[r] += __shfl_xor(rs[r], off);
    }
    #pragma unroll
    for (int r = 0; r < 4; ++r) lrun[r] = lrun[r] * sc[r] + rs[r];
    #pragma unroll
    for (int dt = 0; dt < 8; ++dt)
      #pragma unroll
      for (int r = 0; r < 4; ++r) o[dt][r] *= sc[r];

    // ---- P: acc layout -> A-frag layout via per-wave LDS (aliased on Ks) ----
    #pragma unroll
    for (int nt = 0; nt < 4; ++nt)
      #pragma unroll
      for (int r = 0; r < 4; ++r)
        Ps[(lg * 4 + r) * 68 + nt * 16 + lr] = s[nt][r];

    // ---- O += P V ----
    #pragma unroll
    for (int kc = 0; kc < 2; ++kc){
      float4 p0 = *reinterpret_cast<const float4*>(&Ps[lr * 68 + kc * 32 + lg * 8]);
      float4 p1 = *reinterpret_cast<const float4*>(&Ps[lr * 68 + kc * 32 + lg * 8 + 4]);
      union { bf16x8 v; unsigned short u[8]; } pa;
      pa.u[0] = f2bf(p0.x); pa.u[1] = f2bf(p0.y); pa.u[2] = f2bf(p0.z); pa.u[3] = f2bf(p0.w);
      pa.u[4] = f2bf(p1.x); pa.u[5] = f2bf(p1.y); pa.u[6] = f2bf(p1.z); pa.u[7] = f2bf(p1.w);
      #pragma unroll
      for (int dt = 0; dt < 8; ++dt){
        bf16x8 vf = *reinterpret_cast<const bf16x8*>(&Vs[dt * 16 + lr][kc * 32 + lg * 8]);
        o[dt] = __builtin_amdgcn_mfma_f32_16x16x32_bf16(pa.v, vf, o[dt], 0, 0, 0);
      }
    }
    __syncthreads();   // Ps (=Ks) and Vs free for next tile's staging
  }

  // ---- epilogue: O /= l; write AO in (B,T,C) bf16 ----
  float inv[4];
  #pragma unroll
  for (int r = 0; r < 4; ++r) inv[r] = 1.0f / lrun[r];
  #pragma unroll
  for (int dt = 0; dt < 8; ++dt)
    #pragma unroll
    for (int r = 0; r < 4; ++r)
      AO[((size_t)b * T_SEQ + qw + lg * 4 + r) * CDIM + h * HD + dt * 16 + lr] =
          f2bf(o[dt][r] * inv[r]);
}

// ---------------- launch ----------------
extern "C" void kernel_launch(void* const* d_in, const int* in_sizes, int n_in,
                              void* d_out, int out_size, void* d_ws, size_t ws_size,
                              hipStream_t stream)
{
  (void)in_sizes; (void)n_in; (void)out_size; (void)ws_size;
  const float* x    = (const float*)d_in[0];
  const float* cosp = (const float*)d_in[1];
  const float* sinp = (const float*)d_in[2];
  const float* Wq   = (const float*)d_in[3];
  const float* Wk   = (const float*)d_in[4];
  const float* Wv   = (const float*)d_in[5];
  const float* Wo   = (const float*)d_in[6];
  float* out = (float*)d_out;

  // workspace layout (all bf16), ~105 MB total
  unsigned short* xb    = (unsigned short*)d_ws;
  unsigned short* Wqkvb = xb    + (size_t)MROWS * CDIM;
  unsigned short* Wob   = Wqkvb + (size_t)NQKV * CDIM;
  unsigned short* QKVb  = Wob   + (size_t)CDIM * CDIM;
  unsigned short* Qb    = QKVb  + (size_t)MROWS * NQKV;
  unsigned short* Kb    = Qb    + (size_t)MROWS * CDIM;
  unsigned short* Vtb   = Kb    + (size_t)MROWS * CDIM;
  unsigned short* AO    = Vtb   + (size_t)MROWS * CDIM;

  int n4x = MROWS * CDIM / 4;
  cvt_f32_bf16<<<(n4x + 255) / 256, 256, 0, stream>>>(x, xb, n4x);
  int n4w = CDIM * CDIM / 4;
  cvt_f32_bf16<<<(n4w + 255) / 256, 256, 0, stream>>>(Wq, Wqkvb, n4w);
  cvt_f32_bf16<<<(n4w + 255) / 256, 256, 0, stream>>>(Wk, Wqkvb + (size_t)CDIM * CDIM, n4w);
  cvt_f32_bf16<<<(n4w + 255) / 256, 256, 0, stream>>>(Wv, Wqkvb + (size_t)2 * CDIM * CDIM, n4w);
  cvt_f32_bf16<<<(n4w + 255) / 256, 256, 0, stream>>>(Wo, Wob, n4w);

  // fused QKV projection: (8192x768) @ (2304x768)^T -> bf16 QKV
  gemm_bt<1><<<dim3(MROWS / 128, NQKV / 128), 256, 0, stream>>>(xb, Wqkvb, QKVb, MROWS, NQKV, CDIM);
  // RoPE + RMSNorm -> Q,K in (B,H,T,D)
  rope_rms<<<dim3(MROWS, 3), 256, 0, stream>>>(QKVb, cosp, sinp, Qb, Kb);
  // V transpose -> Vt (B*H, D, T)
  transpose_v<<<dim3(T_SEQ / 64, 12, 4), 256, 0, stream>>>(QKVb, Vtb);
  // causal flash attention -> AO in (B,T,C)
  attn_fwd<<<dim3(T_SEQ / 64, 4 * NH), 256, 0, stream>>>(Qb, Kb, Vtb, AO);
  // output projection -> f32 d_out
  gemm_bt<0><<<dim3(MROWS / 128, CDIM / 128), 256, 0, stream>>>(AO, Wob, out, MROWS, CDIM, CDIM);
}

// Round 4
// 256.527 us; speedup vs baseline: 1.1014x; 1.1014x over previous
//
#include <hip/hip_runtime.h>

#define T_SEQ 2048
#define NH    6
#define HD    128
#define CDIM  768
#define NQKV  2304
#define MROWS 8192   // B*T = 4*2048

typedef __attribute__((ext_vector_type(8))) short bf16x8;
typedef __attribute__((ext_vector_type(4))) float f32x4;

__device__ __forceinline__ unsigned short f2bf(float f){
  unsigned int u = __builtin_bit_cast(unsigned int, f);
  u += 0x7fffu + ((u >> 16) & 1u);          // round-to-nearest-even
  return (unsigned short)(u >> 16);
}
__device__ __forceinline__ float bf2f(unsigned short h){
  unsigned int u = ((unsigned int)h) << 16;
  return __builtin_bit_cast(float, u);
}

// async global->LDS, 16B per lane; LDS dest is wave-uniform base + lane*16
__device__ __forceinline__ void gload_lds16(const void* g, void* l){
  __builtin_amdgcn_global_load_lds(
      (const __attribute__((address_space(1))) unsigned int*)g,
      (__attribute__((address_space(3))) unsigned int*)l, 16, 0, 0);
}

// ---------------- f32 -> bf16 conversion (vectorized) ----------------
__global__ __launch_bounds__(256) void cvt_f32_bf16(
    const float* __restrict__ in, unsigned short* __restrict__ out, int n4){
  int i = blockIdx.x * 256 + threadIdx.x;
  if (i >= n4) return;
  float4 v = reinterpret_cast<const float4*>(in)[i];
  ushort4 o;
  o.x = f2bf(v.x); o.y = f2bf(v.y); o.z = f2bf(v.z); o.w = f2bf(v.w);
  reinterpret_cast<ushort4*>(out)[i] = o;
}

// 4 weight matrices (each CDIM*CDIM f32) -> contiguous bf16 (Wqkv then Wo)
__global__ __launch_bounds__(256) void cvt_w4(
    const float* __restrict__ w0, const float* __restrict__ w1,
    const float* __restrict__ w2, const float* __restrict__ w3,
    unsigned short* __restrict__ out){
  const int which = blockIdx.y;
  const float* src = which == 0 ? w0 : which == 1 ? w1 : which == 2 ? w2 : w3;
  int i = blockIdx.x * 256 + threadIdx.x;           // in float4 units
  float4 v = reinterpret_cast<const float4*>(src)[i];
  ushort4 o;
  o.x = f2bf(v.x); o.y = f2bf(v.y); o.z = f2bf(v.z); o.w = f2bf(v.w);
  reinterpret_cast<ushort4*>(out + (size_t)which * CDIM * CDIM)[i] = o;
}

// ---------------- GEMM: C = A(MxK,bf16) * B(NxK,bf16)^T ----------------
// m97 structure: 128x128 tile, BK=64, global_load_lds(16B) into linear LDS,
// XOR slot-swizzle (slot ^= row&7) applied on global-source AND ds_read side.
template<int BF16OUT>
__global__ __launch_bounds__(256) void gemm_bt(
    const unsigned short* __restrict__ A,
    const unsigned short* __restrict__ B,
    void* __restrict__ Cv, int M, int N, int K)
{
  __shared__ unsigned short As[128 * 64];   // linear, row = 64 elems = 128B
  __shared__ unsigned short Bs[128 * 64];
  const int tid  = threadIdx.x;
  const int lane = tid & 63;
  const int wave = tid >> 6;
  const int wm = wave >> 1, wn = wave & 1;
  const int lr = lane & 15, lg = lane >> 4;
  const int srow = lane >> 3;               // staging row within 8-row seg
  const int sslot = (lane & 7) ^ (lane >> 3);  // pre-swizzled global slot
  const int row0 = blockIdx.x * 128, col0 = blockIdx.y * 128;

  f32x4 acc[4][4];
  const f32x4 z = {0.f, 0.f, 0.f, 0.f};
  #pragma unroll
  for (int i = 0; i < 4; ++i)
    #pragma unroll
    for (int j = 0; j < 4; ++j) acc[i][j] = z;

  for (int k0 = 0; k0 < K; k0 += 64){
    #pragma unroll
    for (int i = 0; i < 4; ++i){
      int seg = wave * 4 + i;                 // 8 rows per 1KB segment
      int r = seg * 8 + srow;
      gload_lds16(&A[(size_t)(row0 + r) * K + k0 + sslot * 8], &As[seg * 512]);
      gload_lds16(&B[(size_t)(col0 + r) * K + k0 + sslot * 8], &Bs[seg * 512]);
    }
    __syncthreads();
    #pragma unroll
    for (int kk = 0; kk < 64; kk += 32){
      bf16x8 af[4], bfr[4];
      #pragma unroll
      for (int mi = 0; mi < 4; ++mi)
        af[mi] = *reinterpret_cast<const bf16x8*>(
            &As[(wm*64 + mi*16 + lr) * 64 + ((((kk>>3) + lg) ^ (lr & 7)) * 8)]);
      #pragma unroll
      for (int ni = 0; ni < 4; ++ni)
        bfr[ni] = *reinterpret_cast<const bf16x8*>(
            &Bs[(wn*64 + ni*16 + lr) * 64 + ((((kk>>3) + lg) ^ (lr & 7)) * 8)]);
      #pragma unroll
      for (int mi = 0; mi < 4; ++mi)
        #pragma unroll
        for (int ni = 0; ni < 4; ++ni)
          acc[mi][ni] = __builtin_amdgcn_mfma_f32_16x16x32_bf16(af[mi], bfr[ni], acc[mi][ni], 0, 0, 0);
    }
    __syncthreads();
  }
  #pragma unroll
  for (int mi = 0; mi < 4; ++mi){
    #pragma unroll
    for (int ni = 0; ni < 4; ++ni){
      #pragma unroll
      for (int r = 0; r < 4; ++r){
        int row = row0 + wm*64 + mi*16 + lg*4 + r;   // C/D: row=(l>>4)*4+reg
        int col = col0 + wn*64 + ni*16 + lr;         //       col=l&15
        if (BF16OUT)
          reinterpret_cast<unsigned short*>(Cv)[(size_t)row * N + col] = f2bf(acc[mi][ni][r]);
        else
          reinterpret_cast<float*>(Cv)[(size_t)row * N + col] = acc[mi][ni][r];
      }
    }
  }
}

// ---------------- RoPE + RMSNorm for Q,K; writes (B,H,T,D) bf16 ----------------
__global__ __launch_bounds__(256) void rope_rms(
    const unsigned short* __restrict__ QKVb,
    const float* __restrict__ cosp, const float* __restrict__ sinp,
    unsigned short* __restrict__ Qb, unsigned short* __restrict__ Kb)
{
  const int bt    = blockIdx.x;            // b*T + t
  const int task  = blockIdx.y * 4 + (threadIdx.x >> 6);   // 0..11
  const int which = task / NH;             // 0=q, 1=k
  const int h     = task % NH;
  const int t     = bt & (T_SEQ - 1);
  const int b     = bt >> 11;
  const int lane  = threadIdx.x & 63;      // 0..63
  const unsigned short* src = QKVb + (size_t)bt * NQKV + which * CDIM + h * HD;
  float x1 = bf2f(src[lane]);
  float x2 = bf2f(src[lane + 64]);
  float c = cosp[t * 64 + lane];
  float s = sinp[t * 64 + lane];
  float y1 = x1 * c + x2 * s;
  float y2 = x2 * c - x1 * s;
  float ss = y1 * y1 + y2 * y2;
  #pragma unroll
  for (int off = 1; off < 64; off <<= 1) ss += __shfl_xor(ss, off);
  float inv = rsqrtf(ss * (1.0f / 128.0f) + 1e-15f);
  unsigned short* dst = (which ? Kb : Qb) + ((size_t)(b * NH + h) * T_SEQ + t) * HD;
  dst[lane]      = f2bf(y1 * inv);
  dst[lane + 64] = f2bf(y2 * inv);
}

// ---------------- V transpose: QKV v-slice (B,T,H,D) -> Vt (B*H, D, T) ----------------
__global__ __launch_bounds__(256) void transpose_v(
    const unsigned short* __restrict__ QKVb, unsigned short* __restrict__ Vt)
{
  __shared__ unsigned short tile[64][66];
  const int tid = threadIdx.x;
  const int t0  = blockIdx.x * 64;          // 32 tiles along T
  const int hd  = blockIdx.y;               // 0..11 : (head, d-half)
  const int b   = blockIdx.z;               // 0..3
  const int h = hd >> 1, dhalf = (hd & 1) * 64;
  const unsigned short* src = QKVb + (size_t)b * T_SEQ * NQKV + 2 * CDIM + h * HD + dhalf;
  #pragma unroll
  for (int it = 0; it < 2; ++it){
    int ch = tid + it * 256;                // 64 rows x 8 chunks
    int r = ch >> 3, cc = (ch & 7) * 8;
    *reinterpret_cast<int4*>(&tile[r][cc]) =
        *reinterpret_cast<const int4*>(&src[(size_t)(t0 + r) * NQKV + cc]);
  }
  __syncthreads();
  unsigned short* dst = Vt + ((size_t)(b * NH + h) * HD + dhalf) * T_SEQ + t0;
  #pragma unroll
  for (int it = 0; it < 2; ++it){
    int ch = tid + it * 256;                // 64 d-rows x 8 chunks
    int d = ch >> 3, cc = (ch & 7) * 8;
    union { int4 v; unsigned short u[8]; } w;
    #pragma unroll
    for (int j = 0; j < 8; ++j) w.u[j] = tile[cc + j][d];
    *reinterpret_cast<int4*>(&dst[(size_t)d * T_SEQ + cc]) = w.v;
  }
}

// ---------------- causal flash attention ----------------
// 4 waves, QBLK=64 (16 q-rows/wave), KVBLK=64, D=128, V pre-transposed.
// Double-buffered K/V via global_load_lds prefetch (issued before compute,
// drained only at end-of-iter __syncthreads). Linear LDS + XOR slot swizzle
// both-sides (rule #21). Ps aliases current K buffer (dead after QK^T).
__global__ __launch_bounds__(256) void attn_fwd(
    const unsigned short* __restrict__ Qb,
    const unsigned short* __restrict__ Kb,
    const unsigned short* __restrict__ Vt,     // (B*H, D, T)
    unsigned short* __restrict__ AO)
{
  __shared__ unsigned short Kd[2][64 * 128];  // 16KB/buf, rows 256B, swizzled
  __shared__ unsigned short Vd[2][128 * 64];  // 16KB/buf, rows 128B, swizzled
  const int tid = threadIdx.x;
  const int lane = tid & 63, wave = tid >> 6;
  const int lr = lane & 15, lg = lane >> 4;
  const int bh = blockIdx.y;
  const int b = bh / NH, h = bh % NH;
  const int q0 = (gridDim.x - 1 - blockIdx.x) * 64;   // big causal blocks first
  const int qw = q0 + wave * 16;
  const int ntile = (q0 >> 6) + 1;
  const unsigned short* Qp = Qb + (size_t)bh * T_SEQ * HD;
  const unsigned short* Kp = Kb + (size_t)bh * T_SEQ * HD;
  const unsigned short* Vp = Vt + (size_t)bh * HD * T_SEQ;

  // staging constants: K 1KB-seg = 4 rows x 16 slots; V 1KB-seg = 8 rows x 8 slots
  const int krr = lane >> 4;                       // K row in 4-row group
  const int vrr = lane >> 3;                       // V row in 8-row group
  const int vgs = (lane & 7) ^ vrr;                // V pre-swizzled global slot

  auto stageK = [&](unsigned short* kb, int kvb){
    #pragma unroll
    for (int i = 0; i < 4; ++i){
      int seg = wave * 4 + i;
      int gs = (lane & 15) ^ (4 * (seg & 1) + krr);    // row&7 = 4(seg&1)+krr
      gload_lds16(Kp + (size_t)(kvb + seg * 4 + krr) * HD + gs * 8, kb + seg * 512);
    }
  };
  auto stageV = [&](unsigned short* vb, int kvb){
    #pragma unroll
    for (int i = 0; i < 4; ++i){
      int seg = wave * 4 + i;
      gload_lds16(Vp + (size_t)(seg * 8 + vrr) * T_SEQ + kvb + vgs * 8, vb + seg * 512);
    }
  };

  // Q fragments in registers: A[m=l&15][k=8*(l>>4)+j], 4 k-chunks of 32
  bf16x8 qf[4];
  #pragma unroll
  for (int c4 = 0; c4 < 4; ++c4)
    qf[c4] = *reinterpret_cast<const bf16x8*>(&Qp[(size_t)(qw + lr) * HD + c4 * 32 + lg * 8]);

  const f32x4 z = {0.f, 0.f, 0.f, 0.f};
  f32x4 o[8];
  #pragma unroll
  for (int dt = 0; dt < 8; ++dt) o[dt] = z;
  float mrun[4], lrun[4];
  #pragma unroll
  for (int r = 0; r < 4; ++r){ mrun[r] = -__builtin_inff(); lrun[r] = 0.f; }
  const float scl = 0.08838834764831845f;   // 1/sqrt(128)

  stageK(&Kd[0][0], 0);
  stageV(&Vd[0][0], 0);
  __syncthreads();                          // drains vmcnt: buf0 ready

  for (int t = 0; t < ntile; ++t){
    const int cur = t & 1;
    unsigned short* kcur = &Kd[cur][0];
    unsigned short* vcur = &Vd[cur][0];
    // ---- issue async prefetch of next tile (stays in flight across mid barrier) ----
    if (t + 1 < ntile){
      stageK(&Kd[cur ^ 1][0], (t + 1) * 64);
      stageV(&Vd[cur ^ 1][0], (t + 1) * 64);
    }

    // ---- S = Q K^T (16 x 64), swizzled reads ----
    f32x4 s[4];
    #pragma unroll
    for (int nt = 0; nt < 4; ++nt) s[nt] = z;
    __builtin_amdgcn_s_setprio(1);
    #pragma unroll
    for (int c4 = 0; c4 < 4; ++c4){
      #pragma unroll
      for (int nt = 0; nt < 4; ++nt){
        bf16x8 kf = *reinterpret_cast<const bf16x8*>(
            &kcur[(nt * 16 + lr) * 128 + (((c4 * 4 + lg) ^ (lr & 7)) * 8)]);
        s[nt] = __builtin_amdgcn_mfma_f32_16x16x32_bf16(qf[c4], kf, s[nt], 0, 0, 0);
      }
    }
    __builtin_amdgcn_s_setprio(0);
    // all waves done reading kcur; do NOT drain vmcnt (prefetch in flight)
    asm volatile("s_waitcnt lgkmcnt(0)" ::: "memory");
    __builtin_amdgcn_s_barrier();

    // ---- scale + causal mask ----
    const int kv0 = t * 64;
    if (kv0 + 63 > qw){
      #pragma unroll
      for (int nt = 0; nt < 4; ++nt){
        int kg = kv0 + nt * 16 + lr;
        #pragma unroll
        for (int r = 0; r < 4; ++r){
          int qg = qw + lg * 4 + r;
          s[nt][r] = (kg <= qg) ? s[nt][r] * scl : -__builtin_inff();
        }
      }
    } else {
      #pragma unroll
      for (int nt = 0; nt < 4; ++nt)
        #pragma unroll
        for (int r = 0; r < 4; ++r) s[nt][r] *= scl;
    }

    // ---- online softmax (per row; 16-lane shuffle reductions) ----
    float pm[4], sc[4], rs[4];
    #pragma unroll
    for (int r = 0; r < 4; ++r)
      pm[r] = fmaxf(fmaxf(s[0][r], s[1][r]), fmaxf(s[2][r], s[3][r]));
    #pragma unroll
    for (int off = 1; off < 16; off <<= 1){
      #pragma unroll
      for (int r = 0; r < 4; ++r) pm[r] = fmaxf(pm[r], __shfl_xor(pm[r], off));
    }
    #pragma unroll
    for (int r = 0; r < 4; ++r){
      float mn = fmaxf(mrun[r], pm[r]);
      sc[r] = (mrun[r] == -__builtin_inff()) ? 0.f : __expf(mrun[r] - mn);
      mrun[r] = mn;
      rs[r] = 0.f;
    }
    #pragma unroll
    for (int nt = 0; nt < 4; ++nt)
      #pragma unroll
      for (int r = 0; r < 4; ++r){
        float p = __expf(s[nt][r] - mrun[r]);
        s[nt][r] = p;
        rs[r] += p;
      }
    #pragma unroll
    for (int off = 1; off < 16; off <<= 1){
      #pragma unroll
      for (int r = 0; r < 4; ++r) rs[r] += __shfl_xor(rs[r], off);
    }
    #pragma unroll
    for (int r = 0; r < 4; ++r) lrun[r] = lrun[r] * sc[r] + rs[r];
    #pragma unroll
    for (int dt = 0; dt < 8; ++dt)
      #pragma unroll
      for (int r = 0; r < 4; ++r) o[dt][r] *= sc[r];

    // ---- P relayout via per-wave buffer aliased on kcur (XOR-swizzled) ----
    float* Ps = reinterpret_cast<float*>(kcur) + wave * 1024;  // 16 x 64 f32
    #pragma unroll
    for (int nt = 0; nt < 4; ++nt)
      #pragma unroll
      for (int r = 0; r < 4; ++r){
        int row = lg * 4 + r;
        Ps[row * 64 + ((nt * 16 + lr) ^ ((row & 7) << 2))] = s[nt][r];
      }

    // ---- O += P V (same-wave Ps read; swizzled vf reads) ----
    __builtin_amdgcn_s_setprio(1);
    #pragma unroll
    for (int kc = 0; kc < 2; ++kc){
      float4 p0 = *reinterpret_cast<const float4*>(
          &Ps[lr * 64 + ((kc * 32 + lg * 8) ^ ((lr & 7) << 2))]);
      float4 p1 = *reinterpret_cast<const float4*>(
          &Ps[lr * 64 + (((kc * 32 + lg * 8) + 4) ^ ((lr & 7) << 2))]);
      union { bf16x8 v; unsigned short u[8]; } pa;
      pa.u[0] = f2bf(p0.x); pa.u[1] = f2bf(p0.y); pa.u[2] = f2bf(p0.z); pa.u[3] = f2bf(p0.w);
      pa.u[4] = f2bf(p1.x); pa.u[5] = f2bf(p1.y); pa.u[6] = f2bf(p1.z); pa.u[7] = f2bf(p1.w);
      #pragma unroll
      for (int dt = 0; dt < 8; ++dt){
        bf16x8 vf = *reinterpret_cast<const bf16x8*>(
            &vcur[(dt * 16 + lr) * 64 + (((kc * 4 + lg) ^ (lr & 7)) * 8)]);
        o[dt] = __builtin_amdgcn_mfma_f32_16x16x32_bf16(pa.v, vf, o[dt], 0, 0, 0);
      }
    }
    __builtin_amdgcn_s_setprio(0);
    __syncthreads();   // drains vmcnt+lgkm: next buf ready, Ps/V reads done
  }

  // ---- epilogue: O /= l; write AO in (B,T,C) bf16 ----
  float inv[4];
  #pragma unroll
  for (int r = 0; r < 4; ++r) inv[r] = 1.0f / lrun[r];
  #pragma unroll
  for (int dt = 0; dt < 8; ++dt)
    #pragma unroll
    for (int r = 0; r < 4; ++r)
      AO[((size_t)b * T_SEQ + qw + lg * 4 + r) * CDIM + h * HD + dt * 16 + lr] =
          f2bf(o[dt][r] * inv[r]);
}

// ---------------- launch ----------------
extern "C" void kernel_launch(void* const* d_in, const int* in_sizes, int n_in,
                              void* d_out, int out_size, void* d_ws, size_t ws_size,
                              hipStream_t stream)
{
  (void)in_sizes; (void)n_in; (void)out_size; (void)ws_size;
  const float* x    = (const float*)d_in[0];
  const float* cosp = (const float*)d_in[1];
  const float* sinp = (const float*)d_in[2];
  const float* Wq   = (const float*)d_in[3];
  const float* Wk   = (const float*)d_in[4];
  const float* Wv   = (const float*)d_in[5];
  const float* Wo   = (const float*)d_in[6];
  float* out = (float*)d_out;

  // workspace layout (all bf16), ~105 MB total
  unsigned short* xb    = (unsigned short*)d_ws;
  unsigned short* Wqkvb = xb    + (size_t)MROWS * CDIM;
  unsigned short* Wob   = Wqkvb + (size_t)NQKV * CDIM;
  unsigned short* QKVb  = Wob   + (size_t)CDIM * CDIM;
  unsigned short* Qb    = QKVb  + (size_t)MROWS * NQKV;
  unsigned short* Kb    = Qb    + (size_t)MROWS * CDIM;
  unsigned short* Vtb   = Kb    + (size_t)MROWS * CDIM;
  unsigned short* AO    = Vtb   + (size_t)MROWS * CDIM;

  int n4x = MROWS * CDIM / 4;
  cvt_f32_bf16<<<(n4x + 255) / 256, 256, 0, stream>>>(x, xb, n4x);
  // 4 weight cvts in one launch (Wqkvb and Wob are contiguous in ws)
  cvt_w4<<<dim3(CDIM * CDIM / 4 / 256, 4), 256, 0, stream>>>(Wq, Wk, Wv, Wo, Wqkvb);

  // fused QKV projection: (8192x768) @ (2304x768)^T -> bf16 QKV
  gemm_bt<1><<<dim3(MROWS / 128, NQKV / 128), 256, 0, stream>>>(xb, Wqkvb, QKVb, MROWS, NQKV, CDIM);
  // RoPE + RMSNorm -> Q,K in (B,H,T,D)
  rope_rms<<<dim3(MROWS, 3), 256, 0, stream>>>(QKVb, cosp, sinp, Qb, Kb);
  // V transpose -> Vt (B*H, D, T)
  transpose_v<<<dim3(T_SEQ / 64, 12, 4), 256, 0, stream>>>(QKVb, Vtb);
  // causal flash attention -> AO in (B,T,C)
  attn_fwd<<<dim3(T_SEQ / 64, 4 * NH), 256, 0, stream>>>(Qb, Kb, Vtb, AO);
  // output projection -> f32 d_out
  gemm_bt<0><<<dim3(MROWS / 128, CDIM / 128), 256, 0, stream>>>(AO, Wob, out, MROWS, CDIM, CDIM);
}